// Round 9
// baseline (11.790 us; speedup 1.0000x reference)
//
#include <hip/hip_runtime.h>
#include <hip/hip_bf16.h>

// Constants from the reference
#define E_DIM 16
#define H_DIM 8
#define F_DIM 48
#define L_IN 384
#define L_OUT 384
#define SZ_B 4

#define NCHUNK 8            // fi-chunks per bh
#define ROWS_PER_BLOCK 48   // 6 fi * 8 vi
#define FI_PER 6
#define TSTRIDE 20          // padded table row stride (floats): 80 B, 16B-aligned b128 rows

typedef float f32x4 __attribute__((ext_vector_type(4)));

// Byte-identical to the round-6 kernel (10.67 us) EXCEPT: plain stores
// instead of nontemporal (A/B isolating the store path; output is
// 2.36 MB/XCD -> L2-absorbable, NT forces in-window HBM drain).
__global__ __launch_bounds__(512)
void bsa_fused_kernel(const float* __restrict__ q,
                      const float* __restrict__ r_voice,
                      const float* __restrict__ e_past,
                      const float* __restrict__ e_future,
                      float* __restrict__ out) {
    const int chunk = blockIdx.x;   // [0, 8)
    const int bh    = blockIdx.y;   // [0, 32)
    const int h     = bh & (H_DIM - 1);
    const int t     = threadIdx.x;  // [0, 512)
    const int w     = t >> 6;
    const int lane  = t & 63;

    // Table rows (stride TSTRIDE): 0..47 past[diff], 48..95 future[diff], 96..159 voice
    __shared__ __attribute__((aligned(16))) float tabs[160 * TSTRIDE];  // 12.8 KB
    __shared__ __attribute__((aligned(16))) float qs[ROWS_PER_BLOCK * E_DIM]; // 3 KB
    __shared__ __attribute__((aligned(16))) float scratch[8 * 64];      // per-wave row results

    // Stage transposed tables (one h-plane). i = f*16+d; flat src = i*8+h.
    for (int i = t; i < F_DIM * E_DIM; i += 512) {
        const int f = i >> 4, d = i & 15;
        tabs[f * TSTRIDE + d]           = e_past [(size_t)i * H_DIM + h];
        tabs[(F_DIM + f) * TSTRIDE + d] = e_future[(size_t)i * H_DIM + h];
    }
    for (int i = t; i < 64 * E_DIM; i += 512) {
        const int r = i >> 4, d = i & 15;
        tabs[(96 + r) * TSTRIDE + d] = r_voice[(size_t)i * H_DIM + h];
    }
    // Stage this block's 48 q-rows (contiguous, coalesced)
    for (int i = t; i < ROWS_PER_BLOCK * E_DIM; i += 512)
        qs[i] = q[((size_t)bh * L_IN + chunk * ROWS_PER_BLOCK) * E_DIM + i];
    __syncthreads();

    float* wscratch = &scratch[w * 64];

    for (int j = 0; j < FI_PER; ++j) {
        const int lrow = w * FI_PER + j;      // [0, 48)
        const int l    = chunk * ROWS_PER_BLOCK + lrow;
        const int fi   = l >> 3;
        const int vi   = l & 7;

        // ---- dot phase: lane k<48 -> T[k]; lanes 48..55 -> V[k-48] ----
        int r;
        if (lane < 48) {
            r = (lane <= fi) ? (fi - lane) : (F_DIM + lane - fi);
        } else {
            int vj = (lane - 48) & 7;         // clamp lanes 56..63 to valid rows
            r = 96 + vi * 8 + vj;
        }
        const f32x4* qv = (const f32x4*)&qs[lrow * E_DIM];
        const f32x4* tv = (const f32x4*)&tabs[r * TSTRIDE];
        f32x4 acc = qv[0] * tv[0] + qv[1] * tv[1] + qv[2] * tv[2] + qv[3] * tv[3];
        const float s = acc.x + acc.y + acc.z + acc.w;
        if (lane < 56) wscratch[lane] = s;
        // Same-wave LDS pipe is in-order; fence stops compiler reordering.
        asm volatile("s_waitcnt lgkmcnt(0)" ::: "memory");
        __builtin_amdgcn_wave_barrier();

        // ---- write phase: 96 float4 (384 floats), lanes cover 64 + 32 ----
        float* orow = out + ((size_t)bh * L_IN + l) * L_OUT;
        #pragma unroll
        for (int rr = 0; rr < 2; ++rr) {
            const int jj = rr * 64 + lane;    // vec4 index [0, 96)
            if (jj < 96) {
                const float tval = wscratch[jj >> 1];           // T[m>>3], m=4*jj
                const f32x4 vv = *(const f32x4*)&wscratch[48 + 4 * (jj & 1)]; // V[m&7 ..]
                f32x4 o;
                o.x = tval + vv.x; o.y = tval + vv.y;
                o.z = tval + vv.z; o.w = tval + vv.w;
                *(f32x4*)(orow + 4 * jj) = o;   // plain store: L2 absorbs
            }
        }
        __builtin_amdgcn_wave_barrier();
    }
}

extern "C" void kernel_launch(void* const* d_in, const int* in_sizes, int n_in,
                              void* d_out, int out_size, void* d_ws, size_t ws_size,
                              hipStream_t stream) {
    const float* q        = (const float*)d_in[0];
    // d_in[1] = flipped_masks (unused)
    const float* r_voice  = (const float*)d_in[2];
    const float* e_past   = (const float*)d_in[3];
    const float* e_future = (const float*)d_in[4];
    float* out = (float*)d_out;

    dim3 grid(NCHUNK, SZ_B * H_DIM);  // (8, 32) = 256 blocks
    bsa_fused_kernel<<<grid, dim3(512), 0, stream>>>(q, r_voice, e_past, e_future, out);
}